// Round 1
// baseline (2355.529 us; speedup 1.0000x reference)
//
#include <hip/hip_runtime.h>

#define T_ROWS 16384
#define H_DIM  4096
#define EPS    1e-5f

typedef _Float16 half8v __attribute__((ext_vector_type(8)));
typedef _Float16 half4v __attribute__((ext_vector_type(4)));
typedef float    floatx4 __attribute__((ext_vector_type(4)));

__device__ __forceinline__ void async_ld16(const void* g, void* l) {
  __builtin_amdgcn_global_load_lds(
      (const __attribute__((address_space(1))) void*)g,
      (__attribute__((address_space(3))) void*)l, 16, 0, 0);
}

// ---------------------------------------------------------------------------
// w (K x N fp32, row-major) -> wt (N x K fp16, row-major)
// ---------------------------------------------------------------------------
__global__ __launch_bounds__(256) void transpose_cast(
    const float* __restrict__ in, _Float16* __restrict__ out) {
  __shared__ float tile[32][33];
  const int tx  = threadIdx.x & 31;
  const int ty4 = (threadIdx.x >> 5) << 2;
  const int nt = blockIdx.x * 32, kt = blockIdx.y * 32;
#pragma unroll
  for (int i = 0; i < 4; ++i)
    tile[ty4 + i][tx] = in[(size_t)(kt + ty4 + i) * H_DIM + nt + tx];
  __syncthreads();
#pragma unroll
  for (int i = 0; i < 4; ++i)
    out[(size_t)(nt + ty4 + i) * H_DIM + kt + tx] = (_Float16)tile[tx][ty4 + i];
}

// ---------------------------------------------------------------------------
// Row-wise RMSNorm (optionally fused relu on the input), H = 4096.
// 256 threads/row, 16 floats/thread held in registers between passes.
// OUT_HALF: write fp16 (GEMM input); else fp32 (final output, may be in-place).
// ---------------------------------------------------------------------------
template <bool RELU, bool OUT_HALF>
__global__ __launch_bounds__(256) void rms_kernel(
    const float* __restrict__ in, const float* __restrict__ g,
    void* __restrict__ out) {
  const int tid = threadIdx.x;
  const float4* rp = (const float4*)(in + (size_t)blockIdx.x * H_DIM);
  float4 v[4];
  float ss = 0.f;
#pragma unroll
  for (int c = 0; c < 4; ++c) {
    float4 t = rp[c * 256 + tid];
    if (RELU) {
      t.x = fmaxf(t.x, 0.f); t.y = fmaxf(t.y, 0.f);
      t.z = fmaxf(t.z, 0.f); t.w = fmaxf(t.w, 0.f);
    }
    v[c] = t;
    ss += t.x * t.x + t.y * t.y + t.z * t.z + t.w * t.w;
  }
#pragma unroll
  for (int off = 32; off > 0; off >>= 1) ss += __shfl_down(ss, off);
  __shared__ float red[4];
  if ((tid & 63) == 0) red[tid >> 6] = ss;
  __syncthreads();
  ss = red[0] + red[1] + red[2] + red[3];
  const float scale = rsqrtf(ss * (1.f / H_DIM) + EPS);
  const float4* gp = (const float4*)g;
#pragma unroll
  for (int c = 0; c < 4; ++c) {
    const float4 gv = gp[c * 256 + tid];
    const float4 t = v[c];
    const float ox = t.x * scale * gv.x, oy = t.y * scale * gv.y,
                oz = t.z * scale * gv.z, ow = t.w * scale * gv.w;
    if (OUT_HALF) {
      half4v h;
      h[0] = (_Float16)ox; h[1] = (_Float16)oy;
      h[2] = (_Float16)oz; h[3] = (_Float16)ow;
      ((half4v*)out)[(size_t)blockIdx.x * 1024 + c * 256 + tid] = h;
    } else {
      float4 o; o.x = ox; o.y = oy; o.z = oz; o.w = ow;
      ((float4*)out)[(size_t)blockIdx.x * 1024 + c * 256 + tid] = o;
    }
  }
}

// ---------------------------------------------------------------------------
// C = A (MxK fp16) @ Bt^T (Bt is NxK fp16) + addend (MxN fp32), out fp32.
// 128x128 tile, BK=32, 256 threads (4 waves, each 64x64 = 4x4 MFMA 16x16x32).
// global_load_lds width-16 staging, 2-barrier K-loop (m97 structure).
// RELU_ADD: addend is relu()'d before adding (recomputes resid = relu(x)).
// ---------------------------------------------------------------------------
template <bool RELU_ADD>
__global__ __launch_bounds__(256) void gemm_fused(
    const _Float16* __restrict__ A, const _Float16* __restrict__ Bt,
    const float* __restrict__ addend, float* __restrict__ out,
    int M, int N, int K) {
  __shared__ __align__(16) _Float16 sA[128 * 32];
  __shared__ __align__(16) _Float16 sB[128 * 32];
  const int tid  = threadIdx.x;
  const int wave = tid >> 6, lane = tid & 63;
  const int quad = lane >> 4, l16 = lane & 15;
  const int wm = (wave >> 1) << 6, wn = (wave & 1) << 6;
  const size_t m0 = (size_t)blockIdx.y * 128, n0 = (size_t)blockIdx.x * 128;

  // staging: each thread issues 2x16B per tile; wave w instr j covers LDS
  // bytes [(j*4+w)*1024, +1024) = rows [(j*4+w)*16, +16), lane -> row=lane/4,
  // kpart=lane%4 (HW places lane data at uniform base + lane*16).
  const int srow = wave * 16 + (lane >> 2);
  const int skp  = lane & 3;
  const _Float16* gA = A  + (m0 + srow) * K + skp * 8;
  const _Float16* gB = Bt + (n0 + srow) * K + skp * 8;
  char* lA = (char*)sA + wave * 1024;
  char* lB = (char*)sB + wave * 1024;

  floatx4 acc[4][4] = {};

  const int kIters = K / 32;
  for (int kb = 0; kb < kIters; ++kb) {
    async_ld16(gA,                  lA);
    async_ld16(gA + (size_t)64 * K, lA + 4096);
    async_ld16(gB,                  lB);
    async_ld16(gB + (size_t)64 * K, lB + 4096);
    gA += 32; gB += 32;
    __syncthreads();
    half8v af[4], bf[4];
#pragma unroll
    for (int i = 0; i < 4; ++i) {
      af[i] = *(const half8v*)(sA + (wm + i * 16 + l16) * 32 + quad * 8);
      bf[i] = *(const half8v*)(sB + (wn + i * 16 + l16) * 32 + quad * 8);
    }
#pragma unroll
    for (int i = 0; i < 4; ++i)
#pragma unroll
      for (int j = 0; j < 4; ++j)
        acc[i][j] = __builtin_amdgcn_mfma_f32_16x16x32_f16(af[i], bf[j],
                                                           acc[i][j], 0, 0, 0);
    __syncthreads();
  }

  // epilogue: C/D layout col = lane&15, row = quad*4 + reg
#pragma unroll
  for (int i = 0; i < 4; ++i) {
#pragma unroll
    for (int r = 0; r < 4; ++r) {
      const size_t m    = m0 + wm + i * 16 + quad * 4 + r;
      const size_t base = m * N + n0 + wn + l16;
#pragma unroll
      for (int j = 0; j < 4; ++j) {
        float a = addend[base + j * 16];
        if (RELU_ADD) a = fmaxf(a, 0.f);
        out[base + j * 16] = acc[i][j][r] + a;
      }
    }
  }
}

// ---------------------------------------------------------------------------
extern "C" void kernel_launch(void* const* d_in, const int* in_sizes, int n_in,
                              void* d_out, int out_size, void* d_ws,
                              size_t ws_size, hipStream_t stream) {
  const float* x  = (const float*)d_in[0];
  const float* g0 = (const float*)d_in[1];
  const float* g1 = (const float*)d_in[2];
  const float* g2 = (const float*)d_in[3];
  const float* w0 = (const float*)d_in[4];
  const float* w1 = (const float*)d_in[5];
  float* out = (float*)d_out;

  char* ws = (char*)d_ws;
  _Float16* w0t  = (_Float16*)ws;                    // 32 MB
  _Float16* w1t  = (_Float16*)(ws + 33554432ull);    // 32 MB
  _Float16* y    = (_Float16*)(ws + 67108864ull);    // 128 MB (reused y0/y1)
  float*    res2 = (float*)   (ws + 201326592ull);   // 256 MB

  const dim3 tgrid(H_DIM / 32, H_DIM / 32);
  transpose_cast<<<tgrid, 256, 0, stream>>>(w0, w0t);
  transpose_cast<<<tgrid, 256, 0, stream>>>(w1, w1t);

  // y0 = rmsnorm(relu(x)) * g0   (fp16)
  rms_kernel<true, true><<<T_ROWS, 256, 0, stream>>>(x, g0, y);

  const dim3 ggrid(H_DIM / 128, T_ROWS / 128);
  // res2 = y0 @ w0 + relu(x)
  gemm_fused<true><<<ggrid, 256, 0, stream>>>(y, w0t, x, res2,
                                              T_ROWS, H_DIM, H_DIM);
  // y1 = rmsnorm(res2) * g1  (fp16)
  rms_kernel<false, true><<<T_ROWS, 256, 0, stream>>>(res2, g1, y);
  // out = y1 @ w1 + res2   (resid3 staged in d_out)
  gemm_fused<false><<<ggrid, 256, 0, stream>>>(y, w1t, res2, out,
                                               T_ROWS, H_DIM, H_DIM);
  // out = rmsnorm(out) * g2, in-place (each block owns its full row)
  rms_kernel<false, false><<<T_ROWS, 256, 0, stream>>>(out, g2, out);
}